// Round 1
// baseline (835.642 us; speedup 1.0000x reference)
//
#include <hip/hip_runtime.h>
#include <math.h>

// SoftAttentionAggregator — fused single-pass kernel.
// B=8 H=256 P=1024 K=32 E=4 BN=64. One 256-thread block per (b,p).
// nf tile (256x32 f32 = 32KB) staged in LDS and read once from HBM.
// Hot loop: per wave, 16 o-outputs/lane over c with wave-uniform w1^T loads
// (w1 transposed into d_ws by a tiny pre-kernel) -> ~1 LDS read : 16 FMA.

#define B_ 8
#define H_ 256
#define P_ 1024
#define K_ 32
#define E_ 4
#define BN_ 64
#define W1ROW 516  // 2H+E

__global__ __launch_bounds__(256) void transpose_w1_kernel(
    const float* __restrict__ w1, float* __restrict__ w1t) {
  int i = blockIdx.x * 256 + threadIdx.x;
  if (i < W1ROW * BN_) {
    int c = i >> 6, o = i & 63;
    w1t[i] = w1[o * W1ROW + c];  // w1t[c][o], row-major 64 wide
  }
}

__global__ __launch_bounds__(256) void soft_attn_agg_kernel(
    const float* __restrict__ cur,   // (B,H,P)
    const float* __restrict__ nf,    // (B,H,P,K)
    const float* __restrict__ nv,    // (B,1,P,K)
    const float* __restrict__ ef,    // (B,E,P,K)
    const float* __restrict__ w1t,   // (516,64) transposed weights
    const float* __restrict__ b1,    // (64)
    const float* __restrict__ w2,    // (64)
    float* __restrict__ out) {       // (B,H,P)
  __shared__ __align__(16) float s_nf[H_][K_];   // 32 KB, row stride 32
  __shared__ float s_cur[H_];
  __shared__ __align__(16) float s_edge[E_][K_];
  __shared__ float s_valid[K_];
  __shared__ float s_part[4][BN_];
  __shared__ float s_proj[BN_];
  __shared__ float s_lp[4][K_];
  __shared__ float s_wt[K_];

  const int t = threadIdx.x;
  const unsigned bid = blockIdx.x;
  // XCD swizzle: same-XCD (bid mod 8) blocks get consecutive p -> L2 locality
  // for strided `cur` reads and strided `out` writes.
  const unsigned xcd = bid & 7u, sidx = bid >> 3;
  const int p = (int)(xcd * 128u + (sidx & 127u));
  const int b = (int)(sidx >> 7);

  // ---- Phase 1: stage nf / cur / edge / validity into LDS ----
  const float* nf_base = nf + (size_t)b * H_ * P_ * K_ + (size_t)p * K_;
#pragma unroll
  for (int i = 0; i < 8; ++i) {
    int q = t + i * 256;          // 0..2047
    int c = q >> 3, kq = q & 7;   // 8 float4 per c-row
    const float4* src =
        (const float4*)(nf_base + (size_t)c * P_ * K_ + kq * 4);
    *((float4*)&s_nf[c][kq * 4]) = *src;
  }
  if (t < H_) s_cur[t] = cur[((size_t)b * H_ + t) * P_ + p];
  if (t < 32) {
    int e = t >> 3, kq = t & 7;
    const float4* src =
        (const float4*)(ef + (((size_t)b * E_ + e) * P_ + p) * K_ + kq * 4);
    *((float4*)&s_edge[e][kq * 4]) = *src;
  }
  if (t >= 32 && t < 64) {
    int k = t - 32;
    s_valid[k] = nv[((size_t)b * P_ + p) * K_ + k];
  }
  __syncthreads();

  // ---- Phase 2: proj[o] = b1[o] + sum_c cur[c]*w1c[o,c] ----
  {
    int o = t & 63, q = t >> 6;
    float partial = 0.f;
    for (int c = q * 64; c < q * 64 + 64; ++c)
      partial = fmaf(s_cur[c], w1t[c * 64 + o], partial);  // coalesced w1^T
    s_part[q][o] = partial;
  }
  __syncthreads();
  if (t < 64)
    s_proj[t] = b1[t] + s_part[0][t] + s_part[1][t] + s_part[2][t] + s_part[3][t];
  __syncthreads();

  // ---- Phase 3: hid[o,k] = relu(proj + nf-term + edge-term); logits ----
  // wave w owns o in [16w, 16w+16); lane = (k, h) with c split in halves.
  const int w = t >> 6;
  const int lane = t & 63;
  const int k = lane & 31;
  const int h = lane >> 5;
  const int o0 = w * 16;
  float acc[16];
#pragma unroll
  for (int j = 0; j < 16; ++j) acc[j] = 0.f;

  const float* w1n = w1t + 256 * 64 + o0;  // rows 256..511 of w1^T
  const int c0 = h * 128;
#pragma unroll 2
  for (int c = c0; c < c0 + 128; ++c) {
    float nfv = s_nf[c][k];  // banks 0..31, 2-way broadcast: free
    const float4* wp = (const float4*)(w1n + (size_t)c * 64);
    float4 wa = wp[0], wb = wp[1], wc = wp[2], wd = wp[3];  // wave-uniform-ish
    acc[0]  = fmaf(wa.x, nfv, acc[0]);
    acc[1]  = fmaf(wa.y, nfv, acc[1]);
    acc[2]  = fmaf(wa.z, nfv, acc[2]);
    acc[3]  = fmaf(wa.w, nfv, acc[3]);
    acc[4]  = fmaf(wb.x, nfv, acc[4]);
    acc[5]  = fmaf(wb.y, nfv, acc[5]);
    acc[6]  = fmaf(wb.z, nfv, acc[6]);
    acc[7]  = fmaf(wb.w, nfv, acc[7]);
    acc[8]  = fmaf(wc.x, nfv, acc[8]);
    acc[9]  = fmaf(wc.y, nfv, acc[9]);
    acc[10] = fmaf(wc.z, nfv, acc[10]);
    acc[11] = fmaf(wc.w, nfv, acc[11]);
    acc[12] = fmaf(wd.x, nfv, acc[12]);
    acc[13] = fmaf(wd.y, nfv, acc[13]);
    acc[14] = fmaf(wd.z, nfv, acc[14]);
    acc[15] = fmaf(wd.w, nfv, acc[15]);
  }

  // epilogue: fold halves, add proj/edge/bias, relu, dot with w2
  {
    const float se0 = s_edge[0][k], se1 = s_edge[1][k];
    const float se2 = s_edge[2][k], se3 = s_edge[3][k];
    const float* w1e = w1t + 512 * 64;
    float lp = 0.f;
#pragma unroll
    for (int j = 0; j < 16; ++j) {
      int o = o0 + j;
      float tot = acc[j] + __shfl_xor(acc[j], 32);
      tot += s_proj[o];
      tot = fmaf(se0, w1e[o], tot);
      tot = fmaf(se1, w1e[64 + o], tot);
      tot = fmaf(se2, w1e[128 + o], tot);
      tot = fmaf(se3, w1e[192 + o], tot);
      tot = fmaxf(tot, 0.f);
      lp = fmaf(tot, w2[o], lp);
    }
    if (h == 0) s_lp[w][k] = lp;
  }
  __syncthreads();

  // ---- Phase 4a: masked softmax over K (one half-wave) ----
  if (t < 32) {
    float lg = s_lp[0][t] + s_lp[1][t] + s_lp[2][t] + s_lp[3][t];
    bool v = s_valid[t] > 0.5f;
    float ml = v ? lg : -INFINITY;
#pragma unroll
    for (int m = 1; m < 32; m <<= 1) ml = fmaxf(ml, __shfl_xor(ml, m));
    float e = v ? __expf(lg - ml) : 0.f;
    float ssum = e;
#pragma unroll
    for (int m = 1; m < 32; m <<= 1) ssum += __shfl_xor(ssum, m);
    // ml == -inf  <=>  no valid neighbor -> all weights zero
    s_wt[t] = (ml > -INFINITY) ? (e / ssum) : 0.f;
  }
  __syncthreads();

  // ---- Phase 4b: pooled[c] = sum_k nf[c][k] * wt[k] ----
  {
    float accp = 0.f;
#pragma unroll
    for (int j = 0; j < 32; ++j) {
      int kk = (t + j) & 31;  // rotation: bank-conflict-free at stride 32
      accp = fmaf(s_nf[t][kk], s_wt[kk], accp);
    }
    out[((size_t)b * H_ + t) * P_ + p] = accp;
  }
}

extern "C" void kernel_launch(void* const* d_in, const int* in_sizes, int n_in,
                              void* d_out, int out_size, void* d_ws,
                              size_t ws_size, hipStream_t stream) {
  const float* cur = (const float*)d_in[0];
  const float* nf  = (const float*)d_in[1];
  const float* nv  = (const float*)d_in[2];
  const float* ef  = (const float*)d_in[3];
  const float* w1  = (const float*)d_in[4];
  const float* b1  = (const float*)d_in[5];
  const float* w2  = (const float*)d_in[6];
  // d_in[7] = b2: softmax is shift-invariant -> b2 never affects the output.

  float* w1t = (float*)d_ws;  // 516*64*4 = 132 KB scratch
  transpose_w1_kernel<<<(W1ROW * BN_ + 255) / 256, 256, 0, stream>>>(w1, w1t);
  soft_attn_agg_kernel<<<B_ * P_, 256, 0, stream>>>(
      cur, nf, nv, ef, w1t, b1, w2, (float*)d_out);
}

// Round 2
// 405.925 us; speedup vs baseline: 2.0586x; 2.0586x over previous
//
#include <hip/hip_runtime.h>
#include <math.h>

// SoftAttentionAggregator — MFMA-based fused kernel (round 2).
// B=8 H=256 P=1024 K=32 E=4 BN=64. One 256-thread block per (b,p).
// Projection = one GEMM: hid[64x32] = W1[64x544] * Z[544x32],
//   Z rows = [cur (bcast over k) | nf | ef | zero-pad], via mfma_f32_16x16x32_bf16.
// W1 pre-packed to bf16 A-frag layout in d_ws. nf staged bf16-transposed in LDS
// (conflict-free ds_write_b64 staging + ds_read_b128 B-frags, 264-elem rows).

#define B_ 8
#define H_ 256
#define P_ 1024
#define K_ 32
#define E_ 4
#define BN_ 64

typedef __attribute__((ext_vector_type(8))) short short8;
typedef __attribute__((ext_vector_type(4))) float floatx4;

__device__ __forceinline__ unsigned short bf16_rne(float f) {
  unsigned u = __float_as_uint(f);
  u += 0x7fffu + ((u >> 16) & 1u);
  return (unsigned short)(u >> 16);
}
__device__ __forceinline__ unsigned pack_bf16_rne(float lo, float hi) {
  unsigned u0 = __float_as_uint(lo);
  u0 += 0x7fffu + ((u0 >> 16) & 1u);
  unsigned u1 = __float_as_uint(hi);
  u1 += 0x7fffu + ((u1 >> 16) & 1u);
  return (u0 >> 16) | (u1 & 0xffff0000u);
}
__device__ __forceinline__ float bf16_to_f(unsigned short u) {
  return __uint_as_float(((unsigned)u) << 16);
}

// Pack w1 (64x516) into bf16 MFMA A-frag layout:
// idx = ((tm*17 + ki)*64 + lane)*8 + j ; o = tm*16 + (lane&15),
// c = ki*32 + (lane>>4)*8 + j ; zero-pad c >= 516.
__global__ __launch_bounds__(256) void prep_kernel(
    const float* __restrict__ w1, unsigned short* __restrict__ w1m) {
  int i = blockIdx.x * 256 + threadIdx.x;
  if (i >= 4 * 17 * 64 * 8) return;  // 34816
  int j = i & 7, lane = (i >> 3) & 63;
  int kt = i >> 9;
  int tm = kt / 17, ki = kt % 17;
  int o = tm * 16 + (lane & 15);
  int c = ki * 32 + (lane >> 4) * 8 + j;
  float v = (c < 516) ? w1[o * 516 + c] : 0.f;
  w1m[i] = bf16_rne(v);
}

__global__ __launch_bounds__(256, 4) void soft_attn_agg_kernel(
    const float* __restrict__ cur,   // (B,H,P)
    const float* __restrict__ nf,    // (B,H,P,K)
    const float* __restrict__ nv,    // (B,1,P,K)
    const float* __restrict__ ef,    // (B,E,P,K)
    const unsigned short* __restrict__ w1m,  // packed A-frags
    const float* __restrict__ b1,    // (64)
    const float* __restrict__ w2,    // (64)
    float* __restrict__ out) {       // (B,H,P)
  constexpr int NFROW = 264;  // 256 + 8 pad (132 dwords/row -> conflict-free)
  __shared__ unsigned short s_nfT[K_][NFROW];  // bf16 nf^T: [k][c], 16.9 KB
  __shared__ unsigned short s_curb[H_];        // bf16 cur
  __shared__ unsigned short s_edgeT[K_][4];    // bf16 ef^T: [k][e]
  __shared__ float s_valid[K_];
  __shared__ float s_b1[BN_];
  __shared__ float s_w2[BN_];
  __shared__ float s_lg[4][2][16];  // [wave(tm)][tn][col] logit partials
  __shared__ float s_wt[K_];

  const int t = threadIdx.x;
  const unsigned bid = blockIdx.x;
  const unsigned xcd = bid & 7u, sidx = bid >> 3;
  const int p = (int)(xcd * 128u + (sidx & 127u));
  const int b = (int)(sidx >> 7);

  const int w = t >> 6;      // wave = tm tile
  const int lane = t & 63;
  const int q = lane >> 4;   // quad
  const int ln15 = lane & 15;

  // ---- Phase 1: staging ----
  // nf: k-major pattern; lane (kk,ch) loads 4 consecutive c at fixed kk.
  // Per instr: lanes 0..31 = 128B contiguous (one c), x2 for ch -> 2x128B.
  const float* nf_base = nf + ((size_t)b * H_ * P_ + (size_t)p) * K_;
  {
    const int kk = lane & 31, ch = lane >> 5;
#pragma unroll
    for (int oc8 = 0; oc8 < 8; ++oc8) {
      const int c = (w * 8 + oc8) * 8 + ch * 4;
      const float* gp = nf_base + (size_t)c * (P_ * K_) + kk;
      float f0 = gp[0];
      float f1 = gp[(size_t)P_ * K_];
      float f2 = gp[(size_t)(2 * P_) * K_];
      float f3 = gp[(size_t)(3 * P_) * K_];
      uint2 d;
      d.x = pack_bf16_rne(f0, f1);
      d.y = pack_bf16_rne(f2, f3);
      *(uint2*)&s_nfT[kk][c] = d;  // ds_write_b64, bank-optimal
    }
  }
  s_curb[t] = bf16_rne(cur[((size_t)b * H_ + t) * P_ + p]);
  if (t < K_) {
    const float* ep = ef + ((size_t)b * E_ * P_ + (size_t)p) * K_ + t;
    float e0 = ep[0];
    float e1 = ep[(size_t)P_ * K_];
    float e2 = ep[(size_t)(2 * P_) * K_];
    float e3 = ep[(size_t)(3 * P_) * K_];
    uint2 d;
    d.x = pack_bf16_rne(e0, e1);
    d.y = pack_bf16_rne(e2, e3);
    *(uint2*)&s_edgeT[t][0] = d;
  } else if (t < 64) {
    s_valid[t - 32] = nv[((size_t)b * P_ + p) * K_ + (t - 32)];
  } else if (t < 128) {
    s_b1[t - 64] = b1[t - 64];
  } else if (t < 192) {
    s_w2[t - 128] = w2[t - 128];
  }
  __syncthreads();

  // ---- Phase 2: MFMA K-loop. Wave w owns o-tile [16w,16w+16), both k-tiles.
  floatx4 acc0, acc1;
  {
    const int ob = w * 16 + q * 4;
    float b0v = s_b1[ob + 0], b1v = s_b1[ob + 1];
    float b2v = s_b1[ob + 2], b3v = s_b1[ob + 3];
    acc0[0] = b0v; acc0[1] = b1v; acc0[2] = b2v; acc0[3] = b3v;
    acc1[0] = b0v; acc1[1] = b1v; acc1[2] = b2v; acc1[3] = b3v;
  }
  const unsigned short* w1m_w = w1m + ((size_t)(w * 17) * 64 + lane) * 8;

  // cur chunks (Z rows 0..255): B-frag broadcast over k columns
#pragma unroll
  for (int ki = 0; ki < 8; ++ki) {
    short8 a = *(const short8*)(w1m_w + (size_t)ki * 512);
    short8 bb = *(const short8*)&s_curb[ki * 32 + q * 8];
    acc0 = __builtin_amdgcn_mfma_f32_16x16x32_bf16(a, bb, acc0, 0, 0, 0);
    acc1 = __builtin_amdgcn_mfma_f32_16x16x32_bf16(a, bb, acc1, 0, 0, 0);
  }
  // nf chunks (Z rows 256..511)
#pragma unroll
  for (int ki = 0; ki < 8; ++ki) {
    short8 a = *(const short8*)(w1m_w + (size_t)(8 + ki) * 512);
    const int c0 = ki * 32 + q * 8;
    short8 b0 = *(const short8*)&s_nfT[ln15][c0];
    short8 b1f = *(const short8*)&s_nfT[16 + ln15][c0];
    acc0 = __builtin_amdgcn_mfma_f32_16x16x32_bf16(a, b0, acc0, 0, 0, 0);
    acc1 = __builtin_amdgcn_mfma_f32_16x16x32_bf16(a, b1f, acc1, 0, 0, 0);
  }
  // edge chunk (Z rows 512..515, zero-padded to 543)
  {
    short8 a = *(const short8*)(w1m_w + (size_t)16 * 512);
    uint2 e0 = *(const uint2*)&s_edgeT[ln15][0];
    uint2 e1 = *(const uint2*)&s_edgeT[16 + ln15][0];
    union { unsigned u[4]; short8 s; } ub0, ub1;
    ub0.u[0] = (q == 0) ? e0.x : 0u;
    ub0.u[1] = (q == 0) ? e0.y : 0u;
    ub0.u[2] = 0u; ub0.u[3] = 0u;
    ub1.u[0] = (q == 0) ? e1.x : 0u;
    ub1.u[1] = (q == 0) ? e1.y : 0u;
    ub1.u[2] = 0u; ub1.u[3] = 0u;
    acc0 = __builtin_amdgcn_mfma_f32_16x16x32_bf16(a, ub0.s, acc0, 0, 0, 0);
    acc1 = __builtin_amdgcn_mfma_f32_16x16x32_bf16(a, ub1.s, acc1, 0, 0, 0);
  }

  // ---- Phase 3: relu, dot w2, reduce rows -> logit partials
  {
    float lp0 = 0.f, lp1 = 0.f;
#pragma unroll
    for (int r = 0; r < 4; ++r) {
      float w2o = s_w2[w * 16 + q * 4 + r];
      lp0 = fmaf(fmaxf(acc0[r], 0.f), w2o, lp0);
      lp1 = fmaf(fmaxf(acc1[r], 0.f), w2o, lp1);
    }
    lp0 += __shfl_xor(lp0, 16);
    lp0 += __shfl_xor(lp0, 32);
    lp1 += __shfl_xor(lp1, 16);
    lp1 += __shfl_xor(lp1, 32);
    if (lane < 16) {
      s_lg[w][0][lane] = lp0;
      s_lg[w][1][lane] = lp1;
    }
  }
  __syncthreads();

  // ---- Phase 4: masked softmax over K=32 (half-wave of wave 0)
  if (t < K_) {
    const int tn = t >> 4, col = t & 15;
    float lg = s_lg[0][tn][col] + s_lg[1][tn][col] + s_lg[2][tn][col] +
               s_lg[3][tn][col];
    bool v = s_valid[t] > 0.5f;
    float ml = v ? lg : -INFINITY;
#pragma unroll
    for (int m = 1; m < 32; m <<= 1) ml = fmaxf(ml, __shfl_xor(ml, m));
    float e = v ? __expf(lg - ml) : 0.f;
    float ssum = e;
#pragma unroll
    for (int m = 1; m < 32; m <<= 1) ssum += __shfl_xor(ssum, m);
    s_wt[t] = (ml > -INFINITY) ? (e / ssum) : 0.f;
  }
  __syncthreads();

  // ---- Phase 5: pooled[c] = sum_k nf[c][k] * wt[k]; thread t = c.
  {
    float accp = 0.f;
#pragma unroll
    for (int kk = 0; kk < K_; kk += 2) {
      float2 wt2 = *(const float2*)&s_wt[kk];
      float f0 = bf16_to_f(s_nfT[kk][t]);
      float f1 = bf16_to_f(s_nfT[kk + 1][t]);
      accp = fmaf(f1, wt2.y, fmaf(f0, wt2.x, accp));
    }
    out[((size_t)b * H_ + t) * P_ + p] = accp;
  }
}

extern "C" void kernel_launch(void* const* d_in, const int* in_sizes, int n_in,
                              void* d_out, int out_size, void* d_ws,
                              size_t ws_size, hipStream_t stream) {
  const float* cur = (const float*)d_in[0];
  const float* nf  = (const float*)d_in[1];
  const float* nv  = (const float*)d_in[2];
  const float* ef  = (const float*)d_in[3];
  const float* w1  = (const float*)d_in[4];
  const float* b1  = (const float*)d_in[5];
  const float* w2  = (const float*)d_in[6];
  // d_in[7] = b2: softmax shift-invariant -> never affects output.

  unsigned short* w1m = (unsigned short*)d_ws;  // 34816 bf16 = 68 KB
  prep_kernel<<<(4 * 17 * 64 * 8 + 255) / 256, 256, 0, stream>>>(w1, w1m);
  soft_attn_agg_kernel<<<B_ * P_, 256, 0, stream>>>(
      cur, nf, nv, ef, w1m, b1, w2, (float*)d_out);
}